// Round 8
// baseline (226.208 us; speedup 1.0000x reference)
//
#include <hip/hip_runtime.h>
#include <math.h>

#define Bn 16
#define Lq 384
#define Hn 12
#define Dm 768
#define DH 64
#define QT2 16
#define NEGV (-1e18f)
#define SPADU 404   // expS/P row stride in ushort
#define ECAP 32     // per-row pair-entry capacity (data max ~8)

typedef __attribute__((ext_vector_type(4))) float f32x4;
typedef __attribute__((ext_vector_type(8))) __bf16 bf16x8;
typedef __attribute__((ext_vector_type(4))) __bf16 bf16x4;
typedef unsigned short ushort_t;
typedef unsigned int uint_t;
typedef unsigned long long ull_t;

__device__ __forceinline__ ushort_t f2b(float f) {
  unsigned int u = __float_as_uint(f);
  unsigned int r = (u + 0x7FFFu + ((u >> 16) & 1u)) >> 16;
  return (ushort_t)r;
}
__device__ __forceinline__ float b2f(ushort_t u) {
  return __uint_as_float(((unsigned int)u) << 16);
}
__device__ __forceinline__ bf16x8 cvt8(float4 a, float4 b) {
  bf16x8 r;
  r[0] = (__bf16)a.x; r[1] = (__bf16)a.y; r[2] = (__bf16)a.z; r[3] = (__bf16)a.w;
  r[4] = (__bf16)b.x; r[5] = (__bf16)b.y; r[6] = (__bf16)b.z; r[7] = (__bf16)b.w;
  return r;
}

// ---------------- merged prologue:
// [0,24): Age/Agr | [24,2328): weight transposes | [2328,2352): win scatter
// [2352,3888): mask bitmask rows (4 rows/block, 1 per wave)
__global__ __launch_bounds__(256) void k_prep(
    const float* __restrict__ Wge, const float* __restrict__ Wgr,
    const float* __restrict__ Vg,
    float* __restrict__ Age, float* __restrict__ Agr,
    const float* __restrict__ W0, const float* __restrict__ W1,
    const float* __restrict__ W2, const float* __restrict__ W3,
    ushort_t* __restrict__ T0, ushort_t* __restrict__ T1,
    ushort_t* __restrict__ T2, ushort_t* __restrict__ T3,
    const int* __restrict__ dp, int* __restrict__ win,
    const int* __restrict__ mask, ull_t* __restrict__ mbits)
{
  __shared__ float vg[DH];
  __shared__ float t[32][33];
  int blk = blockIdx.x;
  if (blk < 24) {
    int which = blk / Hn;
    int h = blk % Hn;
    const float* Wsrc = which ? Wgr : Wge;
    float* dst = which ? Agr : Age;
    if (threadIdx.x < DH) vg[threadIdx.x] = Vg[h*DH + threadIdx.x];
    __syncthreads();
    for (int d = threadIdx.x; d < Dm; d += 256) {
      const float* wrow = Wsrc + (size_t)d*Dm + h*DH;
      float s = 0.f;
      #pragma unroll 8
      for (int j = 0; j < DH; ++j) s = fmaf(wrow[j], vg[j], s);
      dst[h*Dm + d] = s;
    }
  } else if (blk < 24 + 2304) {
    int b2 = blk - 24;
    int z = b2 / 576, rem = b2 % 576;
    const float* W = (z == 0) ? W0 : (z == 1) ? W1 : (z == 2) ? W2 : W3;
    ushort_t* WT = (z == 0) ? T0 : (z == 1) ? T1 : (z == 2) ? T2 : T3;
    int k0 = (rem / 24)*32, n0 = (rem % 24)*32;
    int tx = threadIdx.x & 31, ty = threadIdx.x >> 5;
    #pragma unroll
    for (int r = 0; r < 4; ++r)
      t[ty + r*8][tx] = W[(size_t)(k0 + ty + r*8)*Dm + n0 + tx];
    __syncthreads();
    #pragma unroll
    for (int r = 0; r < 4; ++r)
      WT[(size_t)(n0 + ty + r*8)*Dm + k0 + tx] = f2b(t[tx][ty + r*8]);
  } else if (blk < 2352) {
    int i = (blk - 2328)*256 + threadIdx.x;
    int b = i / Lq, l = i % Lq;
    int p0 = dp[(size_t)(b*2+0)*Lq + l];
    int p1 = dp[(size_t)(b*2+1)*Lq + l];
    atomicMax(&win[(size_t)b*Lq*Lq + (size_t)p0*Lq + p1], l);
  } else {
    int rr = blk - 2352;                 // 0..1535
    int lane = threadIdx.x & 63, wave = threadIdx.x >> 6;
    int gi = rr*4 + wave;                // global row 0..6143
    const int* mrow = mask + (size_t)gi*Lq;
    ull_t w0 = __ballot(mrow[lane]        != 0);
    ull_t w1 = __ballot(mrow[lane + 64]   != 0);
    ull_t w2 = __ballot(mrow[lane + 128]  != 0);
    ull_t w3 = __ballot(mrow[lane + 192]  != 0);
    ull_t w4 = __ballot(mrow[lane + 256]  != 0);
    ull_t w5 = __ballot(mrow[lane + 320]  != 0);
    if (lane == 0) {
      ull_t* out = mbits + (size_t)gi*6;
      out[0] = w0; out[1] = w1; out[2] = w2;
      out[3] = w3; out[4] = w4; out[5] = w5;
    }
  }
}

// ---------------- collect sparse pair entries per row (win + win^T nonzeros)
__global__ __launch_bounds__(256) void k_collect(
    const int* __restrict__ win, uint_t* __restrict__ ent,
    int* __restrict__ rowcnt)
{
  __shared__ int tB[32][33];
  int b = blockIdx.z;
  int i0 = blockIdx.x*32, j0 = blockIdx.y*32;
  const int* wb = win + (size_t)b*Lq*Lq;
  int tx = threadIdx.x & 31, ty = threadIdx.x >> 5;
  #pragma unroll
  for (int rr = 0; rr < 4; ++rr) {
    int r = ty + rr*8;
    tB[r][tx] = wb[(size_t)(j0+r)*Lq + i0 + tx];
  }
  __syncthreads();
  #pragma unroll
  for (int rr = 0; rr < 4; ++rr) {
    int ti = ty + rr*8;
    int i = i0 + ti, j = j0 + tx;
    int l1 = wb[(size_t)i*Lq + j];
    int l2 = tB[tx][ti];
    if (l1 >= 0 || l2 >= 0) {
      int slot = atomicAdd(&rowcnt[(size_t)b*Lq + i], 1);
      if (slot < ECAP)
        ent[((size_t)b*Lq + i)*ECAP + slot] =
            (uint_t)j | ((uint_t)(l1 + 1) << 9) | ((uint_t)(l2 + 1) << 19);
    }
  }
}

// ---------------- g (tanh gate) and rlog; 4 l-rows per block, wave per row
__global__ __launch_bounds__(256) void k_grlog(
    const float* __restrict__ values, const float* __restrict__ relations,
    const int* __restrict__ dp, const int* __restrict__ rel_mask,
    const float* __restrict__ Age, const float* __restrict__ Agr,
    const float* __restrict__ Vr,
    float* __restrict__ g, float* __restrict__ rlog)
{
  int blk = blockIdx.x;
  int b = blk / (Lq/4), l0 = (blk % (Lq/4))*4;
  int tid = threadIdx.x, lane = tid & 63, wave = tid >> 6;
  __shared__ float relrow[4][Dm], hvrow[4][Dm];
  #pragma unroll
  for (int rr = 0; rr < 4; ++rr) {
    int l = l0 + rr;
    int rm = rel_mask[(size_t)b*Lq + l];
    int idx = dp[(size_t)(b*2)*Lq + l];
    const float* vrow = values + ((size_t)b*Lq + idx)*Dm;
    const float* rrow = relations + ((size_t)b*Lq + l)*Dm;
    for (int d = tid; d < Dm; d += 256) {
      relrow[rr][d] = rm ? 0.f : rrow[d];
      hvrow[rr][d]  = (rm || l == 0) ? 0.f : vrow[d];
    }
  }
  __syncthreads();
  int l = l0 + wave;
  for (int h = 0; h < Hn; ++h) {
    float p = 0.f;
    #pragma unroll
    for (int k = 0; k < Dm/64; ++k) {
      int d = lane + 64*k;
      p = fmaf(hvrow[wave][d], Age[h*Dm + d],
          fmaf(relrow[wave][d], Agr[h*Dm + d], p));
    }
    #pragma unroll
    for (int o = 32; o > 0; o >>= 1) p += __shfl_xor(p, o);
    if (lane == 0) g[((size_t)b*Hn + h)*Lq + l] = tanhf(p);
  }
  if (lane < Hn) {
    float s = 0.f;
    #pragma unroll 8
    for (int j = 0; j < DH; ++j)
      s = fmaf(relrow[wave][lane*DH + j], Vr[lane*DH + j], s);
    rlog[((size_t)b*Hn + lane)*Lq + l] = s;
  }
}

// ---------------- fused QKV projection GEMM, f32 A staged+converted in-kernel
// blockIdx.z: 0=q (x0.125), 1=k, 2=v (transposed per-batch output)
__global__ __launch_bounds__(256) void k_mmqkv(
    const float* __restrict__ Xq, const float* __restrict__ Xk,
    const float* __restrict__ Xv,
    const ushort_t* __restrict__ WqT, const ushort_t* __restrict__ WkT,
    const ushort_t* __restrict__ WvT,
    ushort_t* __restrict__ qbf, ushort_t* __restrict__ kbf,
    ushort_t* __restrict__ vTbf)
{
  const int K = Dm;
  __shared__ ushort_t As[128*64];
  __shared__ ushort_t Bs[128*64];

  int z = blockIdx.z;
  const float* A     = (z == 0) ? Xq : (z == 1) ? Xk : Xv;
  const ushort_t* BT = (z == 0) ? WqT : (z == 1) ? WkT : WvT;

  int bm = blockIdx.x;
  int bn = blockIdx.y;
  int m_blk = bm*128;

  int t = threadIdx.x;
  int wave = t >> 6, lane = t & 63;
  int wr = wave >> 1, wc = wave & 1;
  int lrow = lane & 15, lkg = lane >> 4;

  f32x4 acc[4][4];
  #pragma unroll
  for (int i = 0; i < 4; ++i)
    #pragma unroll
    for (int j = 0; j < 4; ++j) acc[i][j] = (f32x4)(0.f);

  int sr = t >> 3, sc8 = t & 7;
  for (int k0 = 0; k0 < K; k0 += 64) {
    __syncthreads();
    #pragma unroll
    for (int i = 0; i < 4; ++i) {
      int row = sr + i*32;
      const float* ap = A + (size_t)(m_blk + row)*K + k0 + sc8*8;
      float4 f0 = *(const float4*)ap;
      float4 f1 = *(const float4*)(ap + 4);
      uint4 vb = *(const uint4*)(BT + (size_t)(bn*128 + row)*K + k0 + sc8*8);
      int slot = sc8 ^ (row & 7);
      *(bf16x8*)&As[row*64 + slot*8] = cvt8(f0, f1);
      *(uint4*)&Bs[row*64 + slot*8] = vb;
    }
    __syncthreads();
    #pragma unroll
    for (int kk = 0; kk < 2; ++kk) {
      bf16x8 aF[4], bF[4];
      int chunk = kk*4 + lkg;
      #pragma unroll
      for (int mi = 0; mi < 4; ++mi) {
        int arow = wr*64 + mi*16 + lrow;
        aF[mi] = *(const bf16x8*)&As[arow*64 + ((chunk ^ (arow & 7)) << 3)];
        int brow = wc*64 + mi*16 + lrow;
        bF[mi] = *(const bf16x8*)&Bs[brow*64 + ((chunk ^ (brow & 7)) << 3)];
      }
      #pragma unroll
      for (int mi = 0; mi < 4; ++mi)
        #pragma unroll
        for (int ni = 0; ni < 4; ++ni)
          acc[mi][ni] = __builtin_amdgcn_mfma_f32_16x16x32_bf16(
              aF[mi], bF[ni], acc[mi][ni], 0, 0, 0);
    }
  }

  float alpha = (z == 0) ? 0.125f : 1.f;
  #pragma unroll
  for (int mi = 0; mi < 4; ++mi) {
    #pragma unroll
    for (int ni = 0; ni < 4; ++ni) {
      f32x4 a = acc[mi][ni];
      int rit = wr*64 + mi*16 + 4*lkg;
      int cit = wc*64 + ni*16 + lrow;
      int gcol = bn*128 + cit;
      if (z < 2) {
        ushort_t* Cb = z ? kbf : qbf;
        int grow = m_blk + rit;
        #pragma unroll
        for (int r = 0; r < 4; ++r)
          Cb[(size_t)(grow + r)*Dm + gcol] = f2b(a[r]*alpha);
      } else {
        int b = bm/3;
        int rl = (bm%3)*128 + rit;
        ushort4 u;
        u.x = f2b(a[0]); u.y = f2b(a[1]); u.z = f2b(a[2]); u.w = f2b(a[3]);
        *(ushort4*)&vTbf[((size_t)b*Dm + gcol)*Lq + rl] = u;
      }
    }
  }
}

// ---------------- 64x128-tile bf16 GEMM. MODE 0: C[M][768] f32 (grid 96,6,1).
// MODE 3: batched aw, per-batch M=N=384, mask epilogue (grid 6,3,16).
template<int MODE>
__global__ __launch_bounds__(256) void k_mm64(
    const ushort_t* __restrict__ A, const ushort_t* __restrict__ BT,
    float* __restrict__ Cf, const int* __restrict__ mask, float alpha)
{
  const int K = Dm;
  __shared__ ushort_t As[64*64];    // 8KB
  __shared__ ushort_t Bs[128*64];   // 16KB

  int bm = blockIdx.x, bn = blockIdx.y, b = blockIdx.z;
  const ushort_t* Ab = (MODE == 3) ? A  + (size_t)b*Lq*Dm : A;
  const ushort_t* Bb = (MODE == 3) ? BT + (size_t)b*Lq*Dm : BT;
  int m0 = bm*64, n0 = bn*128;

  int t = threadIdx.x;
  int wave = t >> 6, lane = t & 63;
  int wr = wave >> 1, wc = wave & 1;
  int lrow = lane & 15, lkg = lane >> 4;

  f32x4 acc[2][4];
  #pragma unroll
  for (int i = 0; i < 2; ++i)
    #pragma unroll
    for (int j = 0; j < 4; ++j) acc[i][j] = (f32x4)(0.f);

  int sr = t >> 3, sc8 = t & 7;
  for (int k0 = 0; k0 < K; k0 += 64) {
    __syncthreads();
    #pragma unroll
    for (int i = 0; i < 2; ++i) {
      int row = sr + i*32;
      uint4 va = *(const uint4*)(Ab + (size_t)(m0 + row)*K + k0 + sc8*8);
      int slot = sc8 ^ (row & 7);
      *(uint4*)&As[row*64 + slot*8] = va;
    }
    #pragma unroll
    for (int i = 0; i < 4; ++i) {
      int row = sr + i*32;
      uint4 vb = *(const uint4*)(Bb + (size_t)(n0 + row)*K + k0 + sc8*8);
      int slot = sc8 ^ (row & 7);
      *(uint4*)&Bs[row*64 + slot*8] = vb;
    }
    __syncthreads();
    #pragma unroll
    for (int kk = 0; kk < 2; ++kk) {
      bf16x8 aF[2], bF[4];
      int chunk = kk*4 + lkg;
      #pragma unroll
      for (int mi = 0; mi < 2; ++mi) {
        int arow = wr*32 + mi*16 + lrow;
        aF[mi] = *(const bf16x8*)&As[arow*64 + ((chunk ^ (arow & 7)) << 3)];
      }
      #pragma unroll
      for (int ni = 0; ni < 4; ++ni) {
        int brow = wc*64 + ni*16 + lrow;
        bF[ni] = *(const bf16x8*)&Bs[brow*64 + ((chunk ^ (brow & 7)) << 3)];
      }
      #pragma unroll
      for (int mi = 0; mi < 2; ++mi)
        #pragma unroll
        for (int ni = 0; ni < 4; ++ni)
          acc[mi][ni] = __builtin_amdgcn_mfma_f32_16x16x32_bf16(
              aF[mi], bF[ni], acc[mi][ni], 0, 0, 0);
    }
  }

  #pragma unroll
  for (int mi = 0; mi < 2; ++mi) {
    #pragma unroll
    for (int ni = 0; ni < 4; ++ni) {
      f32x4 a = acc[mi][ni];
      int rit = wr*32 + mi*16 + 4*lkg;
      int cit = wc*64 + ni*16 + lrow;
      if (MODE == 0) {
        int grow = m0 + rit, gcol = n0 + cit;
        #pragma unroll
        for (int r = 0; r < 4; ++r)
          Cf[(size_t)(grow + r)*Dm + gcol] = a[r]*alpha;
      } else {
        int rl = m0 + rit, cl = n0 + cit;
        const int* mb2 = mask + (size_t)b*Lq*Lq;
        float* awb = Cf + (size_t)b*Lq*Lq;
        #pragma unroll
        for (int r = 0; r < 4; ++r) {
          int m = mb2[(size_t)(rl + r)*Lq + cl];
          awb[(size_t)(rl + r)*Lq + cl] = m ? NEGV : a[r]*alpha;
        }
      }
    }
  }
}

// ---------------- fused per-(b,h,16-q-rows) attention, MFMA QK + PV
// Sparse phase 2: mask bitmask + per-row pair-entry list; P=sw except fixups.
__global__ __launch_bounds__(256, 8) void k_attn3(
    const ushort_t* __restrict__ qbf, const ushort_t* __restrict__ kbf,
    const ushort_t* __restrict__ vT,
    const ull_t* __restrict__ mbits, const int* __restrict__ rowcnt,
    const uint_t* __restrict__ ent,
    const float* __restrict__ g, const float* __restrict__ rlog,
    ushort_t* __restrict__ ctxbf)
{
  __shared__ ushort_t S16[QT2][SPADU];  // 12.9KB: exp(logits) bf16, then P bf16
  __shared__ ull_t mb[QT2][6];          // 768B: mask bitmask rows

  int bid = blockIdx.x;
  int h  = bid % Hn;
  int qt = (bid / Hn) % (Lq/QT2);
  int b  = bid / (Hn * (Lq/QT2));
  int q0 = qt * QT2;
  int tid = threadIdx.x, lane = tid & 63, wave = tid >> 6;
  int lrow = lane & 15, lkg = lane >> 4;
  int w4 = wave*4;

  const float* gh = g    + ((size_t)b*Hn + h)*Lq;
  const float* rh = rlog + ((size_t)b*Hn + h)*Lq;

  if (tid < QT2*6) {
    int r = tid / 6, u = tid % 6;
    mb[r][u] = mbits[((size_t)b*Lq + q0 + r)*6 + u];
  }

  // Phase 1: QK via MFMA, exp applied immediately, bf16 store
  {
    const ushort_t* qb = qbf + ((size_t)b*Lq + q0 + lrow)*Dm + h*DH + lkg*8;
    bf16x8 aF0 = *(const bf16x8*)(qb);
    bf16x8 aF1 = *(const bf16x8*)(qb + 32);
    int col0 = wave*96;
    #pragma unroll
    for (int tt = 0; tt < 6; ++tt) {
      int col = col0 + tt*16 + lrow;
      const ushort_t* kb = kbf + ((size_t)b*Lq + col)*Dm + h*DH + lkg*8;
      bf16x8 bF0 = *(const bf16x8*)(kb);
      bf16x8 bF1 = *(const bf16x8*)(kb + 32);
      f32x4 z = (f32x4)(0.f);
      z = __builtin_amdgcn_mfma_f32_16x16x32_bf16(aF0, bF0, z, 0, 0, 0);
      z = __builtin_amdgcn_mfma_f32_16x16x32_bf16(aF1, bF1, z, 0, 0, 0);
      #pragma unroll
      for (int r = 0; r < 4; ++r)
        S16[4*lkg + r][col] = f2b(__expf(z[r]));
    }
  }
  __syncthreads();

  // Phase 2: sparse dual softmax + gate fixup; wave owns rows w4..w4+3
  for (int r = 0; r < 4; ++r) {
    int row = w4 + r, i = q0 + row;
    ull_t mw[6];
    #pragma unroll
    for (int u = 0; u < 6; ++u) mw[u] = mb[row][u];
    float sv[6];
    float ssum = 0.f;
    #pragma unroll
    for (int u = 0; u < 6; ++u) {
      int kj = u*64 + lane;
      bool mk = (mw[u] >> lane) & 1ull;
      sv[u] = mk ? 0.f : b2f(S16[row][kj]);
      ssum += sv[u];
    }
    #pragma unroll
    for (int o = 32; o > 0; o >>= 1) ssum += __shfl_xor(ssum, o);
    int nun = 384;
    #pragma unroll
    for (int u = 0; u < 6; ++u) nun -= (int)__popcll(mw[u]);
    int cnt = rowcnt[(size_t)b*Lq + i];
    cnt = cnt > ECAP ? ECAP : cnt;
    const uint_t* entrow = ent + ((size_t)b*Lq + i)*ECAP;
    float rext = 0.f;
    for (int e = 0; e < cnt; ++e) {
      uint_t en = entrow[e];
      int j = en & 511;
      if ((mb[row][j >> 6] >> (j & 63)) & 1ull) continue;
      int l1 = (int)((en >> 9) & 1023) - 1;
      int l2 = (int)(en >> 19) - 1;
      float rel = 0.f;
      if (l1 >= 0) rel += rh[l1];
      if (l2 >= 0) rel += rh[l2];
      rext += __expf(rel) - 1.f;
    }
    float rsum = (float)nun + rext;
    float si = 1.f/ssum, ri = 1.f/rsum;
    ushort_t* prow = &S16[row][0];
    #pragma unroll
    for (int u = 0; u < 6; ++u)
      prow[u*64 + lane] = f2b(sv[u]*si);
    for (int e = 0; e < cnt; ++e) {
      uint_t en = entrow[e];
      int j = en & 511;
      if ((mb[row][j >> 6] >> (j & 63)) & 1ull) continue;
      int l1 = (int)((en >> 9) & 1023) - 1;
      int l2 = (int)(en >> 19) - 1;
      float rel = 0.f, gvv = 0.f;
      if (l1 >= 0) { rel += rh[l1]; gvv += gh[l1]; }
      if (l2 >= 0) { rel += rh[l2]; gvv += gh[l2]; }
      float pfix = (1.f - gvv)*b2f(prow[j]) + gvv*__expf(rel)*ri;
      if (lane == 0) prow[j] = f2b(pfix);
    }
  }
  __syncthreads();

  // Phase 3: PV via MFMA; wave covers d-slice [wave*16, +16)
  {
    int dcol = h*DH + wave*16 + lrow;
    const ushort_t* vb = vT + ((size_t)b*Dm + dcol)*Lq + lkg*8;
    const ushort_t* prow = &S16[lrow][0];
    f32x4 o = (f32x4)(0.f);
    #pragma unroll
    for (int ks = 0; ks < 12; ++ks) {
      bf16x4 lo = *(const bf16x4*)(prow + ks*32 + lkg*8);
      bf16x4 hi = *(const bf16x4*)(prow + ks*32 + lkg*8 + 4);
      bf16x8 pa = __builtin_shufflevector(lo, hi, 0,1,2,3,4,5,6,7);
      bf16x8 bv = *(const bf16x8*)(vb + ks*32);
      o = __builtin_amdgcn_mfma_f32_16x16x32_bf16(pa, bv, o, 0, 0, 0);
    }
    #pragma unroll
    for (int r = 0; r < 4; ++r)
      ctxbf[((size_t)b*Lq + q0 + 4*lkg + r)*Dm + dcol] = f2b(o[r]);
  }
}

extern "C" void kernel_launch(void* const* d_in, const int* in_sizes, int n_in,
                              void* d_out, int out_size, void* d_ws, size_t ws_size,
                              hipStream_t stream) {
  const float* queries   = (const float*)d_in[0];
  const float* keys      = (const float*)d_in[1];
  const float* values    = (const float*)d_in[2];
  const float* relations = (const float*)d_in[3];
  const int*   dp_map    = (const int*)d_in[4];
  const int*   mask      = (const int*)d_in[5];
  const int*   rel_mask  = (const int*)d_in[6];
  const float* Wq  = (const float*)d_in[7];
  const float* Wk  = (const float*)d_in[8];
  const float* Wv  = (const float*)d_in[9];
  const float* Wo  = (const float*)d_in[10];
  const float* Wge = (const float*)d_in[11];
  const float* Wgr = (const float*)d_in[12];
  const float* Vr  = (const float*)d_in[13];
  const float* Vg  = (const float*)d_in[14];

  float* ws = (float*)d_ws;
  const size_t SZ   = (size_t)Bn*Lq*Dm;      // 4718592
  const size_t WINS = (size_t)Bn*Lq*Lq;      // 2359296
  const size_t GSZ  = (size_t)Bn*Hn*Lq;      // 73728
  const size_t ROWS = (size_t)Bn*Lq;         // 6144

  int*   win  = (int*)ws;
  float* g    = ws + WINS;
  float* rlog = g + GSZ;
  float* Age  = rlog + GSZ;
  float* Agr  = Age + (size_t)Hn*Dm;
  ull_t* mbits = (ull_t*)(Agr + (size_t)Hn*Dm);   // 8B-aligned (offset div by 8)
  int*   rowcnt = (int*)(mbits + ROWS*6);
  uint_t* ent  = (uint_t*)(rowcnt + ROWS);
  ushort_t* p0 = (ushort_t*)(ent + ROWS*ECAP);
  ushort_t* qbf  = p0;
  ushort_t* kbf  = p0 + SZ;
  ushort_t* vTbf = p0 + 2*SZ;
  ushort_t* ctxbf= p0 + 3*SZ;
  ushort_t* WqT  = p0 + 4*SZ;
  ushort_t* WkT  = WqT + (size_t)Dm*Dm;
  ushort_t* WvT  = WkT + (size_t)Dm*Dm;
  ushort_t* WoT  = WvT + (size_t)Dm*Dm;

  float* outp = (float*)d_out;               // (B,L,D)
  float* awp  = outp + SZ;                   // (B,L,L)

  hipMemsetAsync(win, 0xFF, WINS*sizeof(int), stream);
  hipMemsetAsync(rowcnt, 0, ROWS*sizeof(int), stream);
  k_prep<<<3888, 256, 0, stream>>>(Wge, Wgr, Vg, Age, Agr,
                                   Wq, Wk, Wv, Wo, WqT, WkT, WvT, WoT,
                                   dp_map, win, mask, mbits);
  k_grlog<<<Bn*Lq/4, 256, 0, stream>>>(values, relations, dp_map, rel_mask,
                                       Age, Agr, Vr, g, rlog);
  k_mmqkv<<<dim3(48, 6, 3), 256, 0, stream>>>(queries, keys, values,
                                              WqT, WkT, WvT, qbf, kbf, vTbf);
  k_collect<<<dim3(12, 12, Bn), 256, 0, stream>>>(win, ent, rowcnt);
  k_mm64<3><<<dim3(6, 3, Bn), 256, 0, stream>>>(qbf, kbf, awp, mask, 1.f/12.f);
  k_attn3<<<Bn*(Lq/QT2)*Hn, 256, 0, stream>>>(qbf, kbf, vTbf, mbits, rowcnt,
                                              ent, g, rlog, ctxbf);
  k_mm64<0><<<dim3(96, 6, 1), 256, 0, stream>>>(ctxbf, WoT, outp, nullptr, 1.f);
}

// Round 9
// 203.823 us; speedup vs baseline: 1.1098x; 1.1098x over previous
//
#include <hip/hip_runtime.h>
#include <math.h>

#define Bn 16
#define Lq 384
#define Hn 12
#define Dm 768
#define DH 64
#define QT2 16
#define NEGV (-1e18f)
#define SPADU 404   // expS/P row stride in ushort
#define ECAP 32     // per-row pair-entry capacity (data max ~8)

typedef __attribute__((ext_vector_type(4))) float f32x4;
typedef __attribute__((ext_vector_type(8))) __bf16 bf16x8;
typedef __attribute__((ext_vector_type(4))) __bf16 bf16x4;
typedef unsigned short ushort_t;
typedef unsigned int uint_t;
typedef unsigned long long ull_t;

__device__ __forceinline__ ushort_t f2b(float f) {
  unsigned int u = __float_as_uint(f);
  unsigned int r = (u + 0x7FFFu + ((u >> 16) & 1u)) >> 16;
  return (ushort_t)r;
}
__device__ __forceinline__ float b2f(ushort_t u) {
  return __uint_as_float(((unsigned int)u) << 16);
}
__device__ __forceinline__ bf16x8 cvt8(float4 a, float4 b) {
  bf16x8 r;
  r[0] = (__bf16)a.x; r[1] = (__bf16)a.y; r[2] = (__bf16)a.z; r[3] = (__bf16)a.w;
  r[4] = (__bf16)b.x; r[5] = (__bf16)b.y; r[6] = (__bf16)b.z; r[7] = (__bf16)b.w;
  return r;
}

// ---------------- merged prologue:
// [0,24): Age/Agr | [24,2328): weight transposes | [2328,2352): win scatter
// [2352,3888): mask bitmask rows (4 rows/block, 1 per wave)
__global__ __launch_bounds__(256) void k_prep(
    const float* __restrict__ Wge, const float* __restrict__ Wgr,
    const float* __restrict__ Vg,
    float* __restrict__ Age, float* __restrict__ Agr,
    const float* __restrict__ W0, const float* __restrict__ W1,
    const float* __restrict__ W2, const float* __restrict__ W3,
    ushort_t* __restrict__ T0, ushort_t* __restrict__ T1,
    ushort_t* __restrict__ T2, ushort_t* __restrict__ T3,
    const int* __restrict__ dp, int* __restrict__ win,
    const int* __restrict__ mask, ull_t* __restrict__ mbits)
{
  __shared__ float vg[DH];
  __shared__ float t[32][33];
  int blk = blockIdx.x;
  if (blk < 24) {
    int which = blk / Hn;
    int h = blk % Hn;
    const float* Wsrc = which ? Wgr : Wge;
    float* dst = which ? Agr : Age;
    if (threadIdx.x < DH) vg[threadIdx.x] = Vg[h*DH + threadIdx.x];
    __syncthreads();
    for (int d = threadIdx.x; d < Dm; d += 256) {
      const float* wrow = Wsrc + (size_t)d*Dm + h*DH;
      float s = 0.f;
      #pragma unroll 8
      for (int j = 0; j < DH; ++j) s = fmaf(wrow[j], vg[j], s);
      dst[h*Dm + d] = s;
    }
  } else if (blk < 24 + 2304) {
    int b2 = blk - 24;
    int z = b2 / 576, rem = b2 % 576;
    const float* W = (z == 0) ? W0 : (z == 1) ? W1 : (z == 2) ? W2 : W3;
    ushort_t* WT = (z == 0) ? T0 : (z == 1) ? T1 : (z == 2) ? T2 : T3;
    int k0 = (rem / 24)*32, n0 = (rem % 24)*32;
    int tx = threadIdx.x & 31, ty = threadIdx.x >> 5;
    #pragma unroll
    for (int r = 0; r < 4; ++r)
      t[ty + r*8][tx] = W[(size_t)(k0 + ty + r*8)*Dm + n0 + tx];
    __syncthreads();
    #pragma unroll
    for (int r = 0; r < 4; ++r)
      WT[(size_t)(n0 + ty + r*8)*Dm + k0 + tx] = f2b(t[tx][ty + r*8]);
  } else if (blk < 2352) {
    int i = (blk - 2328)*256 + threadIdx.x;
    int b = i / Lq, l = i % Lq;
    int p0 = dp[(size_t)(b*2+0)*Lq + l];
    int p1 = dp[(size_t)(b*2+1)*Lq + l];
    atomicMax(&win[(size_t)b*Lq*Lq + (size_t)p0*Lq + p1], l);
  } else {
    int rr = blk - 2352;                 // 0..1535
    int lane = threadIdx.x & 63, wave = threadIdx.x >> 6;
    int gi = rr*4 + wave;                // global row 0..6143
    const int* mrow = mask + (size_t)gi*Lq;
    ull_t w0 = __ballot(mrow[lane]        != 0);
    ull_t w1 = __ballot(mrow[lane + 64]   != 0);
    ull_t w2 = __ballot(mrow[lane + 128]  != 0);
    ull_t w3 = __ballot(mrow[lane + 192]  != 0);
    ull_t w4 = __ballot(mrow[lane + 256]  != 0);
    ull_t w5 = __ballot(mrow[lane + 320]  != 0);
    if (lane == 0) {
      ull_t* out = mbits + (size_t)gi*6;
      out[0] = w0; out[1] = w1; out[2] = w2;
      out[3] = w3; out[4] = w4; out[5] = w5;
    }
  }
}

// ---------------- collect sparse pair entries per row (win + win^T nonzeros)
__global__ __launch_bounds__(256) void k_collect(
    const int* __restrict__ win, uint_t* __restrict__ ent,
    int* __restrict__ rowcnt)
{
  __shared__ int tB[32][33];
  int b = blockIdx.z;
  int i0 = blockIdx.x*32, j0 = blockIdx.y*32;
  const int* wb = win + (size_t)b*Lq*Lq;
  int tx = threadIdx.x & 31, ty = threadIdx.x >> 5;
  #pragma unroll
  for (int rr = 0; rr < 4; ++rr) {
    int r = ty + rr*8;
    tB[r][tx] = wb[(size_t)(j0+r)*Lq + i0 + tx];
  }
  __syncthreads();
  #pragma unroll
  for (int rr = 0; rr < 4; ++rr) {
    int ti = ty + rr*8;
    int i = i0 + ti, j = j0 + tx;
    int l1 = wb[(size_t)i*Lq + j];
    int l2 = tB[tx][ti];
    if (l1 >= 0 || l2 >= 0) {
      int slot = atomicAdd(&rowcnt[(size_t)b*Lq + i], 1);
      if (slot < ECAP)
        ent[((size_t)b*Lq + i)*ECAP + slot] =
            (uint_t)j | ((uint_t)(l1 + 1) << 9) | ((uint_t)(l2 + 1) << 19);
    }
  }
}

// ---------------- g (tanh gate) and rlog; 4 l-rows per block, wave per row
__global__ __launch_bounds__(256) void k_grlog(
    const float* __restrict__ values, const float* __restrict__ relations,
    const int* __restrict__ dp, const int* __restrict__ rel_mask,
    const float* __restrict__ Age, const float* __restrict__ Agr,
    const float* __restrict__ Vr,
    float* __restrict__ g, float* __restrict__ rlog)
{
  int blk = blockIdx.x;
  int b = blk / (Lq/4), l0 = (blk % (Lq/4))*4;
  int tid = threadIdx.x, lane = tid & 63, wave = tid >> 6;
  __shared__ float relrow[4][Dm], hvrow[4][Dm];
  #pragma unroll
  for (int rr = 0; rr < 4; ++rr) {
    int l = l0 + rr;
    int rm = rel_mask[(size_t)b*Lq + l];
    int idx = dp[(size_t)(b*2)*Lq + l];
    const float* vrow = values + ((size_t)b*Lq + idx)*Dm;
    const float* rrow = relations + ((size_t)b*Lq + l)*Dm;
    for (int d = tid; d < Dm; d += 256) {
      relrow[rr][d] = rm ? 0.f : rrow[d];
      hvrow[rr][d]  = (rm || l == 0) ? 0.f : vrow[d];
    }
  }
  __syncthreads();
  int l = l0 + wave;
  for (int h = 0; h < Hn; ++h) {
    float p = 0.f;
    #pragma unroll
    for (int k = 0; k < Dm/64; ++k) {
      int d = lane + 64*k;
      p = fmaf(hvrow[wave][d], Age[h*Dm + d],
          fmaf(relrow[wave][d], Agr[h*Dm + d], p));
    }
    #pragma unroll
    for (int o = 32; o > 0; o >>= 1) p += __shfl_xor(p, o);
    if (lane == 0) g[((size_t)b*Hn + h)*Lq + l] = tanhf(p);
  }
  if (lane < Hn) {
    float s = 0.f;
    #pragma unroll 8
    for (int j = 0; j < DH; ++j)
      s = fmaf(relrow[wave][lane*DH + j], Vr[lane*DH + j], s);
    rlog[((size_t)b*Hn + lane)*Lq + l] = s;
  }
}

// ---------------- fused QKV projection GEMM, f32 A staged+converted in-kernel
// blockIdx.z: 0=q (x0.125), 1=k, 2=v (transposed per-batch output)
__global__ __launch_bounds__(256) void k_mmqkv(
    const float* __restrict__ Xq, const float* __restrict__ Xk,
    const float* __restrict__ Xv,
    const ushort_t* __restrict__ WqT, const ushort_t* __restrict__ WkT,
    const ushort_t* __restrict__ WvT,
    ushort_t* __restrict__ qbf, ushort_t* __restrict__ kbf,
    ushort_t* __restrict__ vTbf)
{
  const int K = Dm;
  __shared__ ushort_t As[128*64];
  __shared__ ushort_t Bs[128*64];

  int z = blockIdx.z;
  const float* A     = (z == 0) ? Xq : (z == 1) ? Xk : Xv;
  const ushort_t* BT = (z == 0) ? WqT : (z == 1) ? WkT : WvT;

  int bm = blockIdx.x;
  int bn = blockIdx.y;
  int m_blk = bm*128;

  int t = threadIdx.x;
  int wave = t >> 6, lane = t & 63;
  int wr = wave >> 1, wc = wave & 1;
  int lrow = lane & 15, lkg = lane >> 4;

  f32x4 acc[4][4];
  #pragma unroll
  for (int i = 0; i < 4; ++i)
    #pragma unroll
    for (int j = 0; j < 4; ++j) acc[i][j] = (f32x4)(0.f);

  int sr = t >> 3, sc8 = t & 7;
  for (int k0 = 0; k0 < K; k0 += 64) {
    __syncthreads();
    #pragma unroll
    for (int i = 0; i < 4; ++i) {
      int row = sr + i*32;
      const float* ap = A + (size_t)(m_blk + row)*K + k0 + sc8*8;
      float4 f0 = *(const float4*)ap;
      float4 f1 = *(const float4*)(ap + 4);
      uint4 vb = *(const uint4*)(BT + (size_t)(bn*128 + row)*K + k0 + sc8*8);
      int slot = sc8 ^ (row & 7);
      *(bf16x8*)&As[row*64 + slot*8] = cvt8(f0, f1);
      *(uint4*)&Bs[row*64 + slot*8] = vb;
    }
    __syncthreads();
    #pragma unroll
    for (int kk = 0; kk < 2; ++kk) {
      bf16x8 aF[4], bF[4];
      int chunk = kk*4 + lkg;
      #pragma unroll
      for (int mi = 0; mi < 4; ++mi) {
        int arow = wr*64 + mi*16 + lrow;
        aF[mi] = *(const bf16x8*)&As[arow*64 + ((chunk ^ (arow & 7)) << 3)];
        int brow = wc*64 + mi*16 + lrow;
        bF[mi] = *(const bf16x8*)&Bs[brow*64 + ((chunk ^ (brow & 7)) << 3)];
      }
      #pragma unroll
      for (int mi = 0; mi < 4; ++mi)
        #pragma unroll
        for (int ni = 0; ni < 4; ++ni)
          acc[mi][ni] = __builtin_amdgcn_mfma_f32_16x16x32_bf16(
              aF[mi], bF[ni], acc[mi][ni], 0, 0, 0);
    }
  }

  float alpha = (z == 0) ? 0.125f : 1.f;
  #pragma unroll
  for (int mi = 0; mi < 4; ++mi) {
    #pragma unroll
    for (int ni = 0; ni < 4; ++ni) {
      f32x4 a = acc[mi][ni];
      int rit = wr*64 + mi*16 + 4*lkg;
      int cit = wc*64 + ni*16 + lrow;
      int gcol = bn*128 + cit;
      if (z < 2) {
        ushort_t* Cb = z ? kbf : qbf;
        int grow = m_blk + rit;
        #pragma unroll
        for (int r = 0; r < 4; ++r)
          Cb[(size_t)(grow + r)*Dm + gcol] = f2b(a[r]*alpha);
      } else {
        int b = bm/3;
        int rl = (bm%3)*128 + rit;
        ushort4 u;
        u.x = f2b(a[0]); u.y = f2b(a[1]); u.z = f2b(a[2]); u.w = f2b(a[3]);
        *(ushort4*)&vTbf[((size_t)b*Dm + gcol)*Lq + rl] = u;
      }
    }
  }
}

// ---------------- 64x128-tile bf16 GEMM. MODE 0: C[M][768] f32 (grid 96,6,1).
// MODE 3: batched aw, per-batch M=N=384, mask epilogue (grid 6,3,16).
template<int MODE>
__global__ __launch_bounds__(256) void k_mm64(
    const ushort_t* __restrict__ A, const ushort_t* __restrict__ BT,
    float* __restrict__ Cf, const int* __restrict__ mask, float alpha)
{
  const int K = Dm;
  __shared__ ushort_t As[64*64];    // 8KB
  __shared__ ushort_t Bs[128*64];   // 16KB

  int bm = blockIdx.x, bn = blockIdx.y, b = blockIdx.z;
  const ushort_t* Ab = (MODE == 3) ? A  + (size_t)b*Lq*Dm : A;
  const ushort_t* Bb = (MODE == 3) ? BT + (size_t)b*Lq*Dm : BT;
  int m0 = bm*64, n0 = bn*128;

  int t = threadIdx.x;
  int wave = t >> 6, lane = t & 63;
  int wr = wave >> 1, wc = wave & 1;
  int lrow = lane & 15, lkg = lane >> 4;

  f32x4 acc[2][4];
  #pragma unroll
  for (int i = 0; i < 2; ++i)
    #pragma unroll
    for (int j = 0; j < 4; ++j) acc[i][j] = (f32x4)(0.f);

  int sr = t >> 3, sc8 = t & 7;
  for (int k0 = 0; k0 < K; k0 += 64) {
    __syncthreads();
    #pragma unroll
    for (int i = 0; i < 2; ++i) {
      int row = sr + i*32;
      uint4 va = *(const uint4*)(Ab + (size_t)(m0 + row)*K + k0 + sc8*8);
      int slot = sc8 ^ (row & 7);
      *(uint4*)&As[row*64 + slot*8] = va;
    }
    #pragma unroll
    for (int i = 0; i < 4; ++i) {
      int row = sr + i*32;
      uint4 vb = *(const uint4*)(Bb + (size_t)(n0 + row)*K + k0 + sc8*8);
      int slot = sc8 ^ (row & 7);
      *(uint4*)&Bs[row*64 + slot*8] = vb;
    }
    __syncthreads();
    #pragma unroll
    for (int kk = 0; kk < 2; ++kk) {
      bf16x8 aF[2], bF[4];
      int chunk = kk*4 + lkg;
      #pragma unroll
      for (int mi = 0; mi < 2; ++mi) {
        int arow = wr*32 + mi*16 + lrow;
        aF[mi] = *(const bf16x8*)&As[arow*64 + ((chunk ^ (arow & 7)) << 3)];
      }
      #pragma unroll
      for (int ni = 0; ni < 4; ++ni) {
        int brow = wc*64 + ni*16 + lrow;
        bF[ni] = *(const bf16x8*)&Bs[brow*64 + ((chunk ^ (brow & 7)) << 3)];
      }
      #pragma unroll
      for (int mi = 0; mi < 2; ++mi)
        #pragma unroll
        for (int ni = 0; ni < 4; ++ni)
          acc[mi][ni] = __builtin_amdgcn_mfma_f32_16x16x32_bf16(
              aF[mi], bF[ni], acc[mi][ni], 0, 0, 0);
    }
  }

  #pragma unroll
  for (int mi = 0; mi < 2; ++mi) {
    #pragma unroll
    for (int ni = 0; ni < 4; ++ni) {
      f32x4 a = acc[mi][ni];
      int rit = wr*32 + mi*16 + 4*lkg;
      int cit = wc*64 + ni*16 + lrow;
      if (MODE == 0) {
        int grow = m0 + rit, gcol = n0 + cit;
        #pragma unroll
        for (int r = 0; r < 4; ++r)
          Cf[(size_t)(grow + r)*Dm + gcol] = a[r]*alpha;
      } else {
        int rl = m0 + rit, cl = n0 + cit;
        const int* mb2 = mask + (size_t)b*Lq*Lq;
        float* awb = Cf + (size_t)b*Lq*Lq;
        #pragma unroll
        for (int r = 0; r < 4; ++r) {
          int m = mb2[(size_t)(rl + r)*Lq + cl];
          awb[(size_t)(rl + r)*Lq + cl] = m ? NEGV : a[r]*alpha;
        }
      }
    }
  }
}

// ---------------- fused per-(b,h,16-q-rows) attention, MFMA QK + PV
// Sparse phase 2, with ALL phase-2 inputs prefetched to LDS before phase 1
// (issues under QK MFMA; kills the R8 serial-dependent-load stall).
__global__ __launch_bounds__(256, 8) void k_attn3(
    const ushort_t* __restrict__ qbf, const ushort_t* __restrict__ kbf,
    const ushort_t* __restrict__ vT,
    const ull_t* __restrict__ mbits, const int* __restrict__ rowcnt,
    const uint_t* __restrict__ ent,
    const float* __restrict__ g, const float* __restrict__ rlog,
    ushort_t* __restrict__ ctxbf)
{
  __shared__ ushort_t S16[QT2][SPADU];  // 12.9KB: exp(logits) bf16, then P bf16
  __shared__ ull_t mb[QT2][6];          // 768B: mask bitmask rows
  __shared__ float2 rg2[Lq + 1];        // 3.1KB: (rlog, g), zero slot at 0
  __shared__ uint_t entS[QT2*ECAP];     // 2KB: pair entries for the 16 rows
  __shared__ int cntS[QT2];             // 64B

  int bid = blockIdx.x;
  int h  = bid % Hn;
  int qt = (bid / Hn) % (Lq/QT2);
  int b  = bid / (Hn * (Lq/QT2));
  int q0 = qt * QT2;
  int tid = threadIdx.x, lane = tid & 63, wave = tid >> 6;
  int lrow = lane & 15, lkg = lane >> 4;
  int w4 = wave*4;

  const float* gh = g    + ((size_t)b*Hn + h)*Lq;
  const float* rh = rlog + ((size_t)b*Hn + h)*Lq;

  // ---- prefetch all phase-2 inputs (overlaps phase-1 MFMA/exp) ----
  if (tid < QT2*6) {
    int r = tid / 6, u = tid % 6;
    mb[r][u] = mbits[((size_t)b*Lq + q0 + r)*6 + u];
  }
  if (tid == 0) { rg2[0].x = 0.f; rg2[0].y = 0.f; }
  for (int e = tid; e < Lq; e += 256) {
    float2 v2; v2.x = rh[e]; v2.y = gh[e];
    rg2[e + 1] = v2;
  }
  #pragma unroll
  for (int e = tid; e < QT2*ECAP; e += 256)
    entS[e] = ent[((size_t)b*Lq + q0)*ECAP + e];
  if (tid < QT2) {
    int c = rowcnt[(size_t)b*Lq + q0 + tid];
    cntS[tid] = c > ECAP ? ECAP : c;
  }

  // Phase 1: QK via MFMA, exp applied immediately, bf16 store
  {
    const ushort_t* qb = qbf + ((size_t)b*Lq + q0 + lrow)*Dm + h*DH + lkg*8;
    bf16x8 aF0 = *(const bf16x8*)(qb);
    bf16x8 aF1 = *(const bf16x8*)(qb + 32);
    int col0 = wave*96;
    #pragma unroll
    for (int tt = 0; tt < 6; ++tt) {
      int col = col0 + tt*16 + lrow;
      const ushort_t* kb = kbf + ((size_t)b*Lq + col)*Dm + h*DH + lkg*8;
      bf16x8 bF0 = *(const bf16x8*)(kb);
      bf16x8 bF1 = *(const bf16x8*)(kb + 32);
      f32x4 z = (f32x4)(0.f);
      z = __builtin_amdgcn_mfma_f32_16x16x32_bf16(aF0, bF0, z, 0, 0, 0);
      z = __builtin_amdgcn_mfma_f32_16x16x32_bf16(aF1, bF1, z, 0, 0, 0);
      #pragma unroll
      for (int r = 0; r < 4; ++r)
        S16[4*lkg + r][col] = f2b(__expf(z[r]));
    }
  }
  __syncthreads();

  // Phase 2: sparse dual softmax + gate fixup; all inputs in LDS
  for (int r = 0; r < 4; ++r) {
    int row = w4 + r;
    ull_t mw[6];
    #pragma unroll
    for (int u = 0; u < 6; ++u) mw[u] = mb[row][u];
    float sv[6];
    float ssum = 0.f;
    #pragma unroll
    for (int u = 0; u < 6; ++u) {
      int kj = u*64 + lane;
      bool mk = (mw[u] >> lane) & 1ull;
      sv[u] = mk ? 0.f : b2f(S16[row][kj]);
      ssum += sv[u];
    }
    #pragma unroll
    for (int o = 32; o > 0; o >>= 1) ssum += __shfl_xor(ssum, o);
    int nun = 384;
    #pragma unroll
    for (int u = 0; u < 6; ++u) nun -= (int)__popcll(mw[u]);
    int cnt = cntS[row];
    const uint_t* erow = &entS[row*ECAP];
    float rext = 0.f;
    for (int e = 0; e < cnt; ++e) {
      uint_t en = erow[e];
      int j = en & 511;
      if ((mw[j >> 6] >> (j & 63)) & 1ull) continue;
      uint_t i1 = (en >> 9) & 1023;
      uint_t i2 = en >> 19;
      float rel = rg2[i1].x + rg2[i2].x;
      rext += __expf(rel) - 1.f;
    }
    float rsum = (float)nun + rext;
    float si = 1.f/ssum, ri = 1.f/rsum;
    ushort_t* prow = &S16[row][0];
    #pragma unroll
    for (int u = 0; u < 6; ++u)
      prow[u*64 + lane] = f2b(sv[u]*si);
    for (int e = 0; e < cnt; ++e) {
      uint_t en = erow[e];
      int j = en & 511;
      if ((mw[j >> 6] >> (j & 63)) & 1ull) continue;
      uint_t i1 = (en >> 9) & 1023;
      uint_t i2 = en >> 19;
      float rel = rg2[i1].x + rg2[i2].x;
      float gvv = rg2[i1].y + rg2[i2].y;
      float pfix = (1.f - gvv)*b2f(prow[j]) + gvv*__expf(rel)*ri;
      if (lane == 0) prow[j] = f2b(pfix);
    }
  }
  __syncthreads();

  // Phase 3: PV via MFMA; wave covers d-slice [wave*16, +16)
  {
    int dcol = h*DH + wave*16 + lrow;
    const ushort_t* vb = vT + ((size_t)b*Dm + dcol)*Lq + lkg*8;
    const ushort_t* prow = &S16[lrow][0];
    f32x4 o = (f32x4)(0.f);
    #pragma unroll
    for (int ks = 0; ks < 12; ++ks) {
      bf16x4 lo = *(const bf16x4*)(prow + ks*32 + lkg*8);
      bf16x4 hi = *(const bf16x4*)(prow + ks*32 + lkg*8 + 4);
      bf16x8 pa = __builtin_shufflevector(lo, hi, 0,1,2,3,4,5,6,7);
      bf16x8 bv = *(const bf16x8*)(vb + ks*32);
      o = __builtin_amdgcn_mfma_f32_16x16x32_bf16(pa, bv, o, 0, 0, 0);
    }
    #pragma unroll
    for (int r = 0; r < 4; ++r)
      ctxbf[((size_t)b*Lq + q0 + 4*lkg + r)*Dm + dcol] = f2b(o[r]);
  }
}

extern "C" void kernel_launch(void* const* d_in, const int* in_sizes, int n_in,
                              void* d_out, int out_size, void* d_ws, size_t ws_size,
                              hipStream_t stream) {
  const float* queries   = (const float*)d_in[0];
  const float* keys      = (const float*)d_in[1];
  const float* values    = (const float*)d_in[2];
  const float* relations = (const float*)d_in[3];
  const int*   dp_map    = (const int*)d_in[4];
  const int*   mask      = (const int*)d_in[5];
  const int*   rel_mask  = (const int*)d_in[6];
  const float* Wq  = (const float*)d_in[7];
  const float* Wk  = (const float*)d_in[8];
  const float* Wv  = (const float*)d_in[9];
  const float* Wo  = (const float*)d_in[10];
  const float* Wge = (const float*)d_in[11];
  const float* Wgr = (const float*)d_in[12];
  const float* Vr  = (const float*)d_in[13];
  const float* Vg  = (const float*)d_in[14];

  float* ws = (float*)d_ws;
  const size_t SZ   = (size_t)Bn*Lq*Dm;      // 4718592
  const size_t WINS = (size_t)Bn*Lq*Lq;      // 2359296
  const size_t GSZ  = (size_t)Bn*Hn*Lq;      // 73728
  const size_t ROWS = (size_t)Bn*Lq;         // 6144

  int*   win  = (int*)ws;
  float* g    = ws + WINS;
  float* rlog = g + GSZ;
  float* Age  = rlog + GSZ;
  float* Agr  = Age + (size_t)Hn*Dm;
  ull_t* mbits = (ull_t*)(Agr + (size_t)Hn*Dm);
  int*   rowcnt = (int*)(mbits + ROWS*6);
  uint_t* ent  = (uint_t*)(rowcnt + ROWS);
  ushort_t* p0 = (ushort_t*)(ent + ROWS*ECAP);
  ushort_t* qbf  = p0;
  ushort_t* kbf  = p0 + SZ;
  ushort_t* vTbf = p0 + 2*SZ;
  ushort_t* ctxbf= p0 + 3*SZ;
  ushort_t* WqT  = p0 + 4*SZ;
  ushort_t* WkT  = WqT + (size_t)Dm*Dm;
  ushort_t* WvT  = WkT + (size_t)Dm*Dm;
  ushort_t* WoT  = WvT + (size_t)Dm*Dm;

  float* outp = (float*)d_out;               // (B,L,D)
  float* awp  = outp + SZ;                   // (B,L,L)

  hipMemsetAsync(win, 0xFF, WINS*sizeof(int), stream);
  hipMemsetAsync(rowcnt, 0, ROWS*sizeof(int), stream);
  k_prep<<<3888, 256, 0, stream>>>(Wge, Wgr, Vg, Age, Agr,
                                   Wq, Wk, Wv, Wo, WqT, WkT, WvT, WoT,
                                   dp_map, win, mask, mbits);
  k_grlog<<<Bn*Lq/4, 256, 0, stream>>>(values, relations, dp_map, rel_mask,
                                       Age, Agr, Vr, g, rlog);
  k_mmqkv<<<dim3(48, 6, 3), 256, 0, stream>>>(queries, keys, values,
                                              WqT, WkT, WvT, qbf, kbf, vTbf);
  k_collect<<<dim3(12, 12, Bn), 256, 0, stream>>>(win, ent, rowcnt);
  k_mm64<3><<<dim3(6, 3, Bn), 256, 0, stream>>>(qbf, kbf, awp, mask, 1.f/12.f);
  k_attn3<<<Bn*(Lq/QT2)*Hn, 256, 0, stream>>>(qbf, kbf, vTbf, mbits, rowcnt,
                                              ent, g, rlog, ctxbf);
  k_mm64<0><<<dim3(96, 6, 1), 256, 0, stream>>>(ctxbf, WoT, outp, nullptr, 1.f);
}

// Round 10
// 200.482 us; speedup vs baseline: 1.1283x; 1.0167x over previous
//
#include <hip/hip_runtime.h>
#include <math.h>

#define Bn 16
#define Lq 384
#define Hn 12
#define Dm 768
#define DH 64
#define QT2 16
#define NEGV (-1e18f)
#define SPADU 404   // e/P row stride in ushort
#define ECAP 32     // per-row pair-entry capacity (data max ~8)

typedef __attribute__((ext_vector_type(4))) float f32x4;
typedef __attribute__((ext_vector_type(8))) __bf16 bf16x8;
typedef __attribute__((ext_vector_type(4))) __bf16 bf16x4;
typedef unsigned short ushort_t;
typedef unsigned int uint_t;
typedef unsigned long long ull_t;

__device__ __forceinline__ ushort_t f2b(float f) {
  return __builtin_bit_cast(ushort_t, (__bf16)f);   // native RNE cvt, 1 op
}
__device__ __forceinline__ float b2f(ushort_t u) {
  return __uint_as_float(((unsigned int)u) << 16);
}
__device__ __forceinline__ bf16x8 cvt8(float4 a, float4 b) {
  bf16x8 r;
  r[0] = (__bf16)a.x; r[1] = (__bf16)a.y; r[2] = (__bf16)a.z; r[3] = (__bf16)a.w;
  r[4] = (__bf16)b.x; r[5] = (__bf16)b.y; r[6] = (__bf16)b.z; r[7] = (__bf16)b.w;
  return r;
}

// ---------------- merged prologue:
// [0,24): Age/Agr | [24,2328): weight transposes | [2328,2352): win scatter
// [2352,3888): mask bitmask rows (4 rows/block, 1 per wave)
__global__ __launch_bounds__(256) void k_prep(
    const float* __restrict__ Wge, const float* __restrict__ Wgr,
    const float* __restrict__ Vg,
    float* __restrict__ Age, float* __restrict__ Agr,
    const float* __restrict__ W0, const float* __restrict__ W1,
    const float* __restrict__ W2, const float* __restrict__ W3,
    ushort_t* __restrict__ T0, ushort_t* __restrict__ T1,
    ushort_t* __restrict__ T2, ushort_t* __restrict__ T3,
    const int* __restrict__ dp, int* __restrict__ win,
    const int* __restrict__ mask, ull_t* __restrict__ mbits)
{
  __shared__ float vg[DH];
  __shared__ float t[32][33];
  int blk = blockIdx.x;
  if (blk < 24) {
    int which = blk / Hn;
    int h = blk % Hn;
    const float* Wsrc = which ? Wgr : Wge;
    float* dst = which ? Agr : Age;
    if (threadIdx.x < DH) vg[threadIdx.x] = Vg[h*DH + threadIdx.x];
    __syncthreads();
    for (int d = threadIdx.x; d < Dm; d += 256) {
      const float* wrow = Wsrc + (size_t)d*Dm + h*DH;
      float s = 0.f;
      #pragma unroll 8
      for (int j = 0; j < DH; ++j) s = fmaf(wrow[j], vg[j], s);
      dst[h*Dm + d] = s;
    }
  } else if (blk < 24 + 2304) {
    int b2 = blk - 24;
    int z = b2 / 576, rem = b2 % 576;
    const float* W = (z == 0) ? W0 : (z == 1) ? W1 : (z == 2) ? W2 : W3;
    ushort_t* WT = (z == 0) ? T0 : (z == 1) ? T1 : (z == 2) ? T2 : T3;
    int k0 = (rem / 24)*32, n0 = (rem % 24)*32;
    int tx = threadIdx.x & 31, ty = threadIdx.x >> 5;
    #pragma unroll
    for (int r = 0; r < 4; ++r)
      t[ty + r*8][tx] = W[(size_t)(k0 + ty + r*8)*Dm + n0 + tx];
    __syncthreads();
    #pragma unroll
    for (int r = 0; r < 4; ++r)
      WT[(size_t)(n0 + ty + r*8)*Dm + k0 + tx] = f2b(t[tx][ty + r*8]);
  } else if (blk < 2352) {
    int i = (blk - 2328)*256 + threadIdx.x;
    int b = i / Lq, l = i % Lq;
    int p0 = dp[(size_t)(b*2+0)*Lq + l];
    int p1 = dp[(size_t)(b*2+1)*Lq + l];
    atomicMax(&win[(size_t)b*Lq*Lq + (size_t)p0*Lq + p1], l);
  } else {
    int rr = blk - 2352;                 // 0..1535
    int lane = threadIdx.x & 63, wave = threadIdx.x >> 6;
    int gi = rr*4 + wave;                // global row 0..6143
    const int* mrow = mask + (size_t)gi*Lq;
    ull_t w0 = __ballot(mrow[lane]        != 0);
    ull_t w1 = __ballot(mrow[lane + 64]   != 0);
    ull_t w2 = __ballot(mrow[lane + 128]  != 0);
    ull_t w3 = __ballot(mrow[lane + 192]  != 0);
    ull_t w4 = __ballot(mrow[lane + 256]  != 0);
    ull_t w5 = __ballot(mrow[lane + 320]  != 0);
    if (lane == 0) {
      ull_t* out = mbits + (size_t)gi*6;
      out[0] = w0; out[1] = w1; out[2] = w2;
      out[3] = w3; out[4] = w4; out[5] = w5;
    }
  }
}

// ---------------- collect sparse pair entries per row (win + win^T nonzeros)
__global__ __launch_bounds__(256) void k_collect(
    const int* __restrict__ win, uint_t* __restrict__ ent,
    int* __restrict__ rowcnt)
{
  __shared__ int tB[32][33];
  int b = blockIdx.z;
  int i0 = blockIdx.x*32, j0 = blockIdx.y*32;
  const int* wb = win + (size_t)b*Lq*Lq;
  int tx = threadIdx.x & 31, ty = threadIdx.x >> 5;
  #pragma unroll
  for (int rr = 0; rr < 4; ++rr) {
    int r = ty + rr*8;
    tB[r][tx] = wb[(size_t)(j0+r)*Lq + i0 + tx];
  }
  __syncthreads();
  #pragma unroll
  for (int rr = 0; rr < 4; ++rr) {
    int ti = ty + rr*8;
    int i = i0 + ti, j = j0 + tx;
    int l1 = wb[(size_t)i*Lq + j];
    int l2 = tB[tx][ti];
    if (l1 >= 0 || l2 >= 0) {
      int slot = atomicAdd(&rowcnt[(size_t)b*Lq + i], 1);
      if (slot < ECAP)
        ent[((size_t)b*Lq + i)*ECAP + slot] =
            (uint_t)j | ((uint_t)(l1 + 1) << 9) | ((uint_t)(l2 + 1) << 19);
    }
  }
}

// ---------------- g (tanh gate) and rlog; 4 l-rows per block, wave per row
__global__ __launch_bounds__(256) void k_grlog(
    const float* __restrict__ values, const float* __restrict__ relations,
    const int* __restrict__ dp, const int* __restrict__ rel_mask,
    const float* __restrict__ Age, const float* __restrict__ Agr,
    const float* __restrict__ Vr,
    float* __restrict__ g, float* __restrict__ rlog)
{
  int blk = blockIdx.x;
  int b = blk / (Lq/4), l0 = (blk % (Lq/4))*4;
  int tid = threadIdx.x, lane = tid & 63, wave = tid >> 6;
  __shared__ float relrow[4][Dm], hvrow[4][Dm];
  #pragma unroll
  for (int rr = 0; rr < 4; ++rr) {
    int l = l0 + rr;
    int rm = rel_mask[(size_t)b*Lq + l];
    int idx = dp[(size_t)(b*2)*Lq + l];
    const float* vrow = values + ((size_t)b*Lq + idx)*Dm;
    const float* rrow = relations + ((size_t)b*Lq + l)*Dm;
    for (int d = tid; d < Dm; d += 256) {
      relrow[rr][d] = rm ? 0.f : rrow[d];
      hvrow[rr][d]  = (rm || l == 0) ? 0.f : vrow[d];
    }
  }
  __syncthreads();
  int l = l0 + wave;
  for (int h = 0; h < Hn; ++h) {
    float p = 0.f;
    #pragma unroll
    for (int k = 0; k < Dm/64; ++k) {
      int d = lane + 64*k;
      p = fmaf(hvrow[wave][d], Age[h*Dm + d],
          fmaf(relrow[wave][d], Agr[h*Dm + d], p));
    }
    #pragma unroll
    for (int o = 32; o > 0; o >>= 1) p += __shfl_xor(p, o);
    if (lane == 0) g[((size_t)b*Hn + h)*Lq + l] = tanhf(p);
  }
  if (lane < Hn) {
    float s = 0.f;
    #pragma unroll 8
    for (int j = 0; j < DH; ++j)
      s = fmaf(relrow[wave][lane*DH + j], Vr[lane*DH + j], s);
    rlog[((size_t)b*Hn + lane)*Lq + l] = s;
  }
}

// ---------------- fused QKV projection GEMM, f32 A staged+converted in-kernel
// blockIdx.z: 0=q (x0.125), 1=k, 2=v (transposed per-batch output)
__global__ __launch_bounds__(256) void k_mmqkv(
    const float* __restrict__ Xq, const float* __restrict__ Xk,
    const float* __restrict__ Xv,
    const ushort_t* __restrict__ WqT, const ushort_t* __restrict__ WkT,
    const ushort_t* __restrict__ WvT,
    ushort_t* __restrict__ qbf, ushort_t* __restrict__ kbf,
    ushort_t* __restrict__ vTbf)
{
  const int K = Dm;
  __shared__ ushort_t As[128*64];
  __shared__ ushort_t Bs[128*64];

  int z = blockIdx.z;
  const float* A     = (z == 0) ? Xq : (z == 1) ? Xk : Xv;
  const ushort_t* BT = (z == 0) ? WqT : (z == 1) ? WkT : WvT;

  int bm = blockIdx.x;
  int bn = blockIdx.y;
  int m_blk = bm*128;

  int t = threadIdx.x;
  int wave = t >> 6, lane = t & 63;
  int wr = wave >> 1, wc = wave & 1;
  int lrow = lane & 15, lkg = lane >> 4;

  f32x4 acc[4][4];
  #pragma unroll
  for (int i = 0; i < 4; ++i)
    #pragma unroll
    for (int j = 0; j < 4; ++j) acc[i][j] = (f32x4)(0.f);

  int sr = t >> 3, sc8 = t & 7;
  for (int k0 = 0; k0 < K; k0 += 64) {
    __syncthreads();
    #pragma unroll
    for (int i = 0; i < 4; ++i) {
      int row = sr + i*32;
      const float* ap = A + (size_t)(m_blk + row)*K + k0 + sc8*8;
      float4 f0 = *(const float4*)ap;
      float4 f1 = *(const float4*)(ap + 4);
      uint4 vb = *(const uint4*)(BT + (size_t)(bn*128 + row)*K + k0 + sc8*8);
      int slot = sc8 ^ (row & 7);
      *(bf16x8*)&As[row*64 + slot*8] = cvt8(f0, f1);
      *(uint4*)&Bs[row*64 + slot*8] = vb;
    }
    __syncthreads();
    #pragma unroll
    for (int kk = 0; kk < 2; ++kk) {
      bf16x8 aF[4], bF[4];
      int chunk = kk*4 + lkg;
      #pragma unroll
      for (int mi = 0; mi < 4; ++mi) {
        int arow = wr*64 + mi*16 + lrow;
        aF[mi] = *(const bf16x8*)&As[arow*64 + ((chunk ^ (arow & 7)) << 3)];
        int brow = wc*64 + mi*16 + lrow;
        bF[mi] = *(const bf16x8*)&Bs[brow*64 + ((chunk ^ (brow & 7)) << 3)];
      }
      #pragma unroll
      for (int mi = 0; mi < 4; ++mi)
        #pragma unroll
        for (int ni = 0; ni < 4; ++ni)
          acc[mi][ni] = __builtin_amdgcn_mfma_f32_16x16x32_bf16(
              aF[mi], bF[ni], acc[mi][ni], 0, 0, 0);
    }
  }

  float alpha = (z == 0) ? 0.125f : 1.f;
  #pragma unroll
  for (int mi = 0; mi < 4; ++mi) {
    #pragma unroll
    for (int ni = 0; ni < 4; ++ni) {
      f32x4 a = acc[mi][ni];
      int rit = wr*64 + mi*16 + 4*lkg;
      int cit = wc*64 + ni*16 + lrow;
      int gcol = bn*128 + cit;
      if (z < 2) {
        ushort_t* Cb = z ? kbf : qbf;
        int grow = m_blk + rit;
        #pragma unroll
        for (int r = 0; r < 4; ++r)
          Cb[(size_t)(grow + r)*Dm + gcol] = f2b(a[r]*alpha);
      } else {
        int b = bm/3;
        int rl = (bm%3)*128 + rit;
        ushort4 u;
        u.x = f2b(a[0]); u.y = f2b(a[1]); u.z = f2b(a[2]); u.w = f2b(a[3]);
        *(ushort4*)&vTbf[((size_t)b*Dm + gcol)*Lq + rl] = u;
      }
    }
  }
}

// ---------------- 64x128-tile bf16 GEMM. MODE 0: C[M][768] f32 (grid 96,6,1).
// MODE 3: batched aw, per-batch M=N=384, mask epilogue (grid 6,3,16).
template<int MODE>
__global__ __launch_bounds__(256) void k_mm64(
    const ushort_t* __restrict__ A, const ushort_t* __restrict__ BT,
    float* __restrict__ Cf, const int* __restrict__ mask, float alpha)
{
  const int K = Dm;
  __shared__ ushort_t As[64*64];    // 8KB
  __shared__ ushort_t Bs[128*64];   // 16KB

  int bm = blockIdx.x, bn = blockIdx.y, b = blockIdx.z;
  const ushort_t* Ab = (MODE == 3) ? A  + (size_t)b*Lq*Dm : A;
  const ushort_t* Bb = (MODE == 3) ? BT + (size_t)b*Lq*Dm : BT;
  int m0 = bm*64, n0 = bn*128;

  int t = threadIdx.x;
  int wave = t >> 6, lane = t & 63;
  int wr = wave >> 1, wc = wave & 1;
  int lrow = lane & 15, lkg = lane >> 4;

  f32x4 acc[2][4];
  #pragma unroll
  for (int i = 0; i < 2; ++i)
    #pragma unroll
    for (int j = 0; j < 4; ++j) acc[i][j] = (f32x4)(0.f);

  int sr = t >> 3, sc8 = t & 7;
  for (int k0 = 0; k0 < K; k0 += 64) {
    __syncthreads();
    #pragma unroll
    for (int i = 0; i < 2; ++i) {
      int row = sr + i*32;
      uint4 va = *(const uint4*)(Ab + (size_t)(m0 + row)*K + k0 + sc8*8);
      int slot = sc8 ^ (row & 7);
      *(uint4*)&As[row*64 + slot*8] = va;
    }
    #pragma unroll
    for (int i = 0; i < 4; ++i) {
      int row = sr + i*32;
      uint4 vb = *(const uint4*)(Bb + (size_t)(n0 + row)*K + k0 + sc8*8);
      int slot = sc8 ^ (row & 7);
      *(uint4*)&Bs[row*64 + slot*8] = vb;
    }
    __syncthreads();
    #pragma unroll
    for (int kk = 0; kk < 2; ++kk) {
      bf16x8 aF[2], bF[4];
      int chunk = kk*4 + lkg;
      #pragma unroll
      for (int mi = 0; mi < 2; ++mi) {
        int arow = wr*32 + mi*16 + lrow;
        aF[mi] = *(const bf16x8*)&As[arow*64 + ((chunk ^ (arow & 7)) << 3)];
      }
      #pragma unroll
      for (int ni = 0; ni < 4; ++ni) {
        int brow = wc*64 + ni*16 + lrow;
        bF[ni] = *(const bf16x8*)&Bs[brow*64 + ((chunk ^ (brow & 7)) << 3)];
      }
      #pragma unroll
      for (int mi = 0; mi < 2; ++mi)
        #pragma unroll
        for (int ni = 0; ni < 4; ++ni)
          acc[mi][ni] = __builtin_amdgcn_mfma_f32_16x16x32_bf16(
              aF[mi], bF[ni], acc[mi][ni], 0, 0, 0);
    }
  }

  #pragma unroll
  for (int mi = 0; mi < 2; ++mi) {
    #pragma unroll
    for (int ni = 0; ni < 4; ++ni) {
      f32x4 a = acc[mi][ni];
      int rit = wr*32 + mi*16 + 4*lkg;
      int cit = wc*64 + ni*16 + lrow;
      if (MODE == 0) {
        int grow = m0 + rit, gcol = n0 + cit;
        #pragma unroll
        for (int r = 0; r < 4; ++r)
          Cf[(size_t)(grow + r)*Dm + gcol] = a[r]*alpha;
      } else {
        int rl = m0 + rit, cl = n0 + cit;
        const int* mb2 = mask + (size_t)b*Lq*Lq;
        float* awb = Cf + (size_t)b*Lq*Lq;
        #pragma unroll
        for (int r = 0; r < 4; ++r) {
          int m = mb2[(size_t)(rl + r)*Lq + cl];
          awb[(size_t)(rl + r)*Lq + cl] = m ? NEGV : a[r]*alpha;
        }
      }
    }
  }
}

// ---------------- fused per-(b,h,16-q-rows) attention, MFMA QK + PV
// e kept in regs through reduction; written to LDS once; P never materialized
// (pair entries patched in-place, PV scaled by 1/ssum at the end).
__global__ __launch_bounds__(256, 8) void k_attn3(
    const ushort_t* __restrict__ qbf, const ushort_t* __restrict__ kbf,
    const ushort_t* __restrict__ vT,
    const ull_t* __restrict__ mbits, const int* __restrict__ rowcnt,
    const uint_t* __restrict__ ent,
    const float* __restrict__ g, const float* __restrict__ rlog,
    ushort_t* __restrict__ ctxbf)
{
  __shared__ ushort_t S16[QT2][SPADU];  // 12.9KB: e (exp, masked), patched
  __shared__ ull_t mb[QT2][6];          // 768B: mask bitmask rows
  __shared__ float2 rg2[Lq + 1];        // 3.1KB: (rlog, g), zero slot at 0
  __shared__ uint_t entS[QT2*ECAP];     // 2KB
  __shared__ int cntS[QT2];             // 64B
  __shared__ float pp[QT2][4];          // 256B: per-wave partial ssums
  __shared__ float sinvS[QT2];          // 64B

  int bid = blockIdx.x;
  int h  = bid % Hn;
  int qt = (bid / Hn) % (Lq/QT2);
  int b  = bid / (Hn * (Lq/QT2));
  int q0 = qt * QT2;
  int tid = threadIdx.x, lane = tid & 63, wave = tid >> 6;
  int lrow = lane & 15, lkg = lane >> 4;

  const float* gh = g    + ((size_t)b*Hn + h)*Lq;
  const float* rh = rlog + ((size_t)b*Hn + h)*Lq;

  // ---- prefetch all phase-2 inputs ----
  if (tid < QT2*6) {
    int r = tid / 6, u = tid % 6;
    mb[r][u] = mbits[((size_t)b*Lq + q0 + r)*6 + u];
  }
  if (tid == 0) { rg2[0].x = 0.f; rg2[0].y = 0.f; }
  for (int e = tid; e < Lq; e += 256) {
    float2 v2; v2.x = rh[e]; v2.y = gh[e];
    rg2[e + 1] = v2;
  }
  #pragma unroll
  for (int e = tid; e < QT2*ECAP; e += 256)
    entS[e] = ent[((size_t)b*Lq + q0)*ECAP + e];
  if (tid < QT2) {
    int c = rowcnt[(size_t)b*Lq + q0 + tid];
    cntS[tid] = c > ECAP ? ECAP : c;
  }
  __syncthreads();   // mb visible to phase 1

  // Phase 1: QK MFMA -> mask-zero -> exp -> reg partial sums + single e write
  {
    const ushort_t* qb = qbf + ((size_t)b*Lq + q0 + lrow)*Dm + h*DH + lkg*8;
    bf16x8 aF0 = *(const bf16x8*)(qb);
    bf16x8 aF1 = *(const bf16x8*)(qb + 32);
    int col0 = wave*96;
    int w0 = col0 >> 6;
    ull_t m0[4], m1[4];
    #pragma unroll
    for (int r = 0; r < 4; ++r) {
      m0[r] = mb[4*lkg + r][w0];
      m1[r] = mb[4*lkg + r][w0 + 1];
    }
    float ps[4] = {0.f, 0.f, 0.f, 0.f};
    const ushort_t* kb = kbf + ((size_t)b*Lq + col0 + lrow)*Dm + h*DH + lkg*8;
    #pragma unroll
    for (int tt = 0; tt < 6; ++tt) {
      int col = col0 + tt*16 + lrow;
      bf16x8 bF0 = *(const bf16x8*)(kb);
      bf16x8 bF1 = *(const bf16x8*)(kb + 32);
      kb += 16*Dm;
      f32x4 z = (f32x4)(0.f);
      z = __builtin_amdgcn_mfma_f32_16x16x32_bf16(aF0, bF0, z, 0, 0, 0);
      z = __builtin_amdgcn_mfma_f32_16x16x32_bf16(aF1, bF1, z, 0, 0, 0);
      bool hi = ((col0 + tt*16) >> 6) != w0;
      int sh = col & 63;
      #pragma unroll
      for (int r = 0; r < 4; ++r) {
        ull_t mw = hi ? m1[r] : m0[r];
        bool mk = (mw >> sh) & 1ull;
        float e = mk ? 0.f : __expf(z[r]);
        ps[r] += e;
        S16[4*lkg + r][col] = f2b(e);
      }
    }
    #pragma unroll
    for (int off = 1; off < 16; off <<= 1)
      #pragma unroll
      for (int r = 0; r < 4; ++r) ps[r] += __shfl_xor(ps[r], off);
    if (lrow == 0) {
      #pragma unroll
      for (int r = 0; r < 4; ++r) pp[4*lkg + r][wave] = ps[r];
    }
  }
  __syncthreads();

  // Phase 2: 16 threads — sinv per row + in-place pair patches on e
  if (tid < QT2) {
    int row = tid;
    float ssum = pp[row][0] + pp[row][1] + pp[row][2] + pp[row][3];
    float si = 1.f / ssum;
    sinvS[row] = si;
    int nun = 384;
    #pragma unroll
    for (int u = 0; u < 6; ++u) nun -= (int)__popcll(mb[row][u]);
    int cnt = cntS[row];
    const uint_t* erow = &entS[row*ECAP];
    float rext = 0.f;
    for (int e = 0; e < cnt; ++e) {
      uint_t en = erow[e];
      int j = en & 511;
      if ((mb[row][j >> 6] >> (j & 63)) & 1ull) continue;
      float rel = rg2[(en >> 9) & 1023].x + rg2[en >> 19].x;
      rext += __expf(rel) - 1.f;
    }
    float sr = ssum / ((float)nun + rext);   // ssum * rinv
    for (int e = 0; e < cnt; ++e) {
      uint_t en = erow[e];
      int j = en & 511;
      if ((mb[row][j >> 6] >> (j & 63)) & 1ull) continue;
      float2 a = rg2[(en >> 9) & 1023];
      float2 c = rg2[en >> 19];
      float er = __expf(a.x + c.x);
      float gvv = a.y + c.y;
      float ev = b2f(S16[row][j]);
      S16[row][j] = f2b((1.f - gvv)*ev + gvv*er*sr);
    }
  }
  __syncthreads();

  // Phase 3: PV on e', scaled by sinv[row] at the end
  {
    int dcol = h*DH + wave*16 + lrow;
    const ushort_t* vb = vT + ((size_t)b*Dm + dcol)*Lq + lkg*8;
    const ushort_t* prow = &S16[lrow][0];
    f32x4 o = (f32x4)(0.f);
    #pragma unroll
    for (int ks = 0; ks < 12; ++ks) {
      bf16x4 lo = *(const bf16x4*)(prow + ks*32 + lkg*8);
      bf16x4 hi = *(const bf16x4*)(prow + ks*32 + lkg*8 + 4);
      bf16x8 pa = __builtin_shufflevector(lo, hi, 0,1,2,3,4,5,6,7);
      bf16x8 bv = *(const bf16x8*)(vb + ks*32);
      o = __builtin_amdgcn_mfma_f32_16x16x32_bf16(pa, bv, o, 0, 0, 0);
    }
    #pragma unroll
    for (int r = 0; r < 4; ++r) {
      float si = sinvS[4*lkg + r];
      ctxbf[((size_t)b*Lq + q0 + 4*lkg + r)*Dm + dcol] = f2b(o[r]*si);
    }
  }
}

extern "C" void kernel_launch(void* const* d_in, const int* in_sizes, int n_in,
                              void* d_out, int out_size, void* d_ws, size_t ws_size,
                              hipStream_t stream) {
  const float* queries   = (const float*)d_in[0];
  const float* keys      = (const float*)d_in[1];
  const float* values    = (const float*)d_in[2];
  const float* relations = (const float*)d_in[3];
  const int*   dp_map    = (const int*)d_in[4];
  const int*   mask      = (const int*)d_in[5];
  const int*   rel_mask  = (const int*)d_in[6];
  const float* Wq  = (const float*)d_in[7];
  const float* Wk  = (const float*)d_in[8];
  const float* Wv  = (const float*)d_in[9];
  const float* Wo  = (const float*)d_in[10];
  const float* Wge = (const float*)d_in[11];
  const float* Wgr = (const float*)d_in[12];
  const float* Vr  = (const float*)d_in[13];
  const float* Vg  = (const float*)d_in[14];

  float* ws = (float*)d_ws;
  const size_t SZ   = (size_t)Bn*Lq*Dm;      // 4718592
  const size_t WINS = (size_t)Bn*Lq*Lq;      // 2359296
  const size_t GSZ  = (size_t)Bn*Hn*Lq;      // 73728
  const size_t ROWS = (size_t)Bn*Lq;         // 6144

  int*   win  = (int*)ws;
  float* g    = ws + WINS;
  float* rlog = g + GSZ;
  float* Age  = rlog + GSZ;
  float* Agr  = Age + (size_t)Hn*Dm;
  ull_t* mbits = (ull_t*)(Agr + (size_t)Hn*Dm);
  int*   rowcnt = (int*)(mbits + ROWS*6);
  uint_t* ent  = (uint_t*)(rowcnt + ROWS);
  ushort_t* p0 = (ushort_t*)(ent + ROWS*ECAP);
  ushort_t* qbf  = p0;
  ushort_t* kbf  = p0 + SZ;
  ushort_t* vTbf = p0 + 2*SZ;
  ushort_t* ctxbf= p0 + 3*SZ;
  ushort_t* WqT  = p0 + 4*SZ;
  ushort_t* WkT  = WqT + (size_t)Dm*Dm;
  ushort_t* WvT  = WkT + (size_t)Dm*Dm;
  ushort_t* WoT  = WvT + (size_t)Dm*Dm;

  float* outp = (float*)d_out;               // (B,L,D)
  float* awp  = outp + SZ;                   // (B,L,L)

  hipMemsetAsync(win, 0xFF, WINS*sizeof(int), stream);
  hipMemsetAsync(rowcnt, 0, ROWS*sizeof(int), stream);
  k_prep<<<3888, 256, 0, stream>>>(Wge, Wgr, Vg, Age, Agr,
                                   Wq, Wk, Wv, Wo, WqT, WkT, WvT, WoT,
                                   dp_map, win, mask, mbits);
  k_grlog<<<Bn*Lq/4, 256, 0, stream>>>(values, relations, dp_map, rel_mask,
                                       Age, Agr, Vr, g, rlog);
  k_mmqkv<<<dim3(48, 6, 3), 256, 0, stream>>>(queries, keys, values,
                                              WqT, WkT, WvT, qbf, kbf, vTbf);
  k_collect<<<dim3(12, 12, Bn), 256, 0, stream>>>(win, ent, rowcnt);
  k_mm64<3><<<dim3(6, 3, Bn), 256, 0, stream>>>(qbf, kbf, awp, mask, 1.f/12.f);
  k_attn3<<<Bn*(Lq/QT2)*Hn, 256, 0, stream>>>(qbf, kbf, vTbf, mbits, rowcnt,
                                              ent, g, rlog, ctxbf);
  k_mm64<0><<<dim3(96, 6, 1), 256, 0, stream>>>(ctxbf, WoT, outp, nullptr, 1.f);
}